// Round 4
// baseline (751.181 us; speedup 1.0000x reference)
//
#include <hip/hip_runtime.h>

#define N_NODES  100000
#define N_EDGES  1600000
#define N_GRAPHS 1024
#define NODE_F   100
#define HID      64
#define GLOB_F   3

#define SCAN_CHUNK 1024
#define SCAN_NB    ((N_NODES + SCAN_CHUNK - 1) / SCAN_CHUNK)   // 98

typedef _Float16 half_t;
typedef __attribute__((ext_vector_type(8))) _Float16 half8;

// ---------------- degree (4 edges/thread, int4 loads) ----------------
__global__ void k_indeg(const int* __restrict__ dst, int* __restrict__ indeg, int E) {
    int i = (blockIdx.x * blockDim.x + threadIdx.x) * 4;
    if (i + 4 <= E) {
        int4 d = *reinterpret_cast<const int4*>(dst + i);
        atomicAdd(&indeg[d.x], 1);
        atomicAdd(&indeg[d.y], 1);
        atomicAdd(&indeg[d.z], 1);
        atomicAdd(&indeg[d.w], 1);
    } else {
        for (int j = i; j < E; ++j) atomicAdd(&indeg[dst[j]], 1);
    }
}

// ---------------- multi-block exclusive scan ----------------
__global__ void k_scan1(const int* __restrict__ indeg, int* __restrict__ blocksum, int N) {
    __shared__ int red[256];
    int t = threadIdx.x;
    int base = blockIdx.x * SCAN_CHUNK + t * 4;
    int s = 0;
#pragma unroll
    for (int j = 0; j < 4; ++j) { int i = base + j; if (i < N) s += indeg[i]; }
    red[t] = s;
    __syncthreads();
    for (int off = 128; off > 0; off >>= 1) {
        if (t < off) red[t] += red[t + off];
        __syncthreads();
    }
    if (t == 0) blocksum[blockIdx.x] = red[0];
}

__global__ void k_scan2(int* __restrict__ blocksum, int NB) {
    __shared__ int sh[128];
    int t = threadIdx.x;
    int v = (t < NB) ? blocksum[t] : 0;
    sh[t] = v;
    __syncthreads();
    for (int off = 1; off < 128; off <<= 1) {
        int o = (t >= off) ? sh[t - off] : 0;
        __syncthreads();
        sh[t] += o;
        __syncthreads();
    }
    if (t < NB) blocksum[t] = sh[t] - v;   // exclusive
}

__global__ void k_scan3(const int* __restrict__ indeg, const int* __restrict__ blocksum,
                        int* __restrict__ rowoff, int* __restrict__ cursor,
                        float* __restrict__ dinv, int N) {
    __shared__ int sh[256];
    int t = threadIdx.x;
    int base = blockIdx.x * SCAN_CHUNK + t * 4;
    int loc[4];
    int s = 0;
#pragma unroll
    for (int j = 0; j < 4; ++j) {
        int i = base + j;
        loc[j] = (i < N) ? indeg[i] : 0;
        s += loc[j];
    }
    sh[t] = s;
    __syncthreads();
    for (int off = 1; off < 256; off <<= 1) {
        int o = (t >= off) ? sh[t - off] : 0;
        __syncthreads();
        sh[t] += o;
        __syncthreads();
    }
    int run = blocksum[blockIdx.x] + sh[t] - s;
#pragma unroll
    for (int j = 0; j < 4; ++j) {
        int i = base + j;
        if (i < N) {
            rowoff[i] = run;
            cursor[i] = run;
            dinv[i] = 1.0f / sqrtf((float)(1 + loc[j]));
            run += loc[j];
            if (i == N - 1) rowoff[N] = run;
        }
    }
}

// ---------------- bucket edges by dst (4 edges/thread) ----------------
__global__ void k_bucket(const int* __restrict__ src, const int* __restrict__ dst,
                         int* __restrict__ cursor, int* __restrict__ csrc, int E) {
    int i = (blockIdx.x * blockDim.x + threadIdx.x) * 4;
    if (i + 4 <= E) {
        int4 s = *reinterpret_cast<const int4*>(src + i);
        int4 d = *reinterpret_cast<const int4*>(dst + i);
        int p;
        p = atomicAdd(&cursor[d.x], 1); csrc[p] = s.x;
        p = atomicAdd(&cursor[d.y], 1); csrc[p] = s.y;
        p = atomicAdd(&cursor[d.z], 1); csrc[p] = s.z;
        p = atomicAdd(&cursor[d.w], 1); csrc[p] = s.w;
    } else {
        for (int j = i; j < E; ++j) {
            int p = atomicAdd(&cursor[dst[j]], 1);
            csrc[p] = src[j];
        }
    }
}

// ---------------- dense MM: Y[r,c] = half((X[r,:]@W[:,c]) * dinv[r]) ----------------
template <int K>
__global__ void k_mm(const float* __restrict__ X, const float* __restrict__ W,
                     const float* __restrict__ dinv, half_t* __restrict__ Y, int N) {
    __shared__ float Ws[K * HID];
    __shared__ float Xs[4][K];
    int tid = threadIdx.x;
    for (int i = tid; i < K * HID; i += 256) Ws[i] = W[i];
    int row0 = blockIdx.x * 4;
    for (int i = tid; i < 4 * K; i += 256) {
        int r = row0 + i / K;
        Xs[i / K][i % K] = (r < N) ? X[(long long)r * K + (i % K)] : 0.0f;
    }
    __syncthreads();
    int ty = tid >> 6;
    int c  = tid & 63;
    int r  = row0 + ty;
    if (r < N) {
        float acc = 0.0f;
#pragma unroll
        for (int k = 0; k < K; ++k) acc += Xs[ty][k] * Ws[k * HID + c];
        Y[(long long)r * HID + c] = (half_t)(acc * dinv[r]);
    }
}

// ---------------- per-dst gather, fp16 payload ----------------
// 1 wave per dst node. Lane = 8*g + l: edge slot g (0..7), feature octet l (0..7).
// Each lane loads half8 (16B) -> one wave instruction covers 8 full rows.
template <int RELU, int POOL>
__global__ void k_gather(const half_t* __restrict__ Hs, const int* __restrict__ rowoff,
                         const int* __restrict__ csrc, const float* __restrict__ dinv,
                         const float* __restrict__ b, float* __restrict__ outbuf,
                         const int* __restrict__ batch, float* __restrict__ pooled,
                         float* __restrict__ cnt, int N) {
    int tid = threadIdx.x;
    int d = blockIdx.x * 4 + (tid >> 6);
    if (d >= N) return;
    int lane = tid & 63;
    int g = lane >> 3;
    int l = lane & 7;
    int lo = rowoff[d], hi = rowoff[d + 1];

    float acc[8] = {0, 0, 0, 0, 0, 0, 0, 0};

    int e = lo;
    // main loop: 16 edges per iteration, unconditional loads
    for (; e + 16 <= hi; e += 16) {
        int s0 = csrc[e + g];
        int s1 = csrc[e + 8 + g];
        half8 h0 = *reinterpret_cast<const half8*>(Hs + (size_t)s0 * HID + l * 8);
        half8 h1 = *reinterpret_cast<const half8*>(Hs + (size_t)s1 * HID + l * 8);
#pragma unroll
        for (int j = 0; j < 8; ++j) acc[j] += (float)h0[j];
#pragma unroll
        for (int j = 0; j < 8; ++j) acc[j] += (float)h1[j];
    }
    // tail: up to 15 edges, guarded
    for (; e < hi; e += 8) {
        int ee = e + g;
        if (ee < hi) {
            int s = csrc[ee];
            half8 hv = *reinterpret_cast<const half8*>(Hs + (size_t)s * HID + l * 8);
#pragma unroll
            for (int j = 0; j < 8; ++j) acc[j] += (float)hv[j];
        }
    }
    // self-loop row: add in group 0 only
    if (g == 0) {
        half8 hv = *reinterpret_cast<const half8*>(Hs + (size_t)d * HID + l * 8);
#pragma unroll
        for (int j = 0; j < 8; ++j) acc[j] += (float)hv[j];
    }
    // butterfly-reduce across the 8 edge-slot groups (lanes differing in bits 3..5)
#pragma unroll
    for (int off = 8; off <= 32; off <<= 1) {
#pragma unroll
        for (int j = 0; j < 8; ++j) acc[j] += __shfl_xor(acc[j], off);
    }

    if (g == 0) {   // 8 lanes hold the full 64-feature result
        float dd = dinv[d];
        float v[8];
#pragma unroll
        for (int j = 0; j < 8; ++j) {
            v[j] = acc[j] * dd + b[l * 8 + j];
            if (RELU) v[j] = fmaxf(v[j], 0.0f);
        }
        if (POOL) {
            int gr = batch[d];
#pragma unroll
            for (int j = 0; j < 8; ++j) unsafeAtomicAdd(&pooled[gr * HID + l * 8 + j], v[j]);
            if (l == 0) unsafeAtomicAdd(&cnt[gr], 1.0f);
        } else {
            float4* o = reinterpret_cast<float4*>(outbuf + (size_t)d * HID + l * 8);
            o[0] = make_float4(v[0], v[1], v[2], v[3]);
            o[1] = make_float4(v[4], v[5], v[6], v[7]);
        }
    }
}

// ---------------- MLP head: one wave per graph ----------------
__global__ void k_head(const float* __restrict__ pooled, const float* __restrict__ cnt,
                       const float* __restrict__ gf,
                       const float* __restrict__ gW1, const float* __restrict__ gb1,
                       const float* __restrict__ gW2, const float* __restrict__ gb2,
                       const float* __restrict__ cW1, const float* __restrict__ cb1,
                       const float* __restrict__ cW2, const float* __restrict__ cb2,
                       float* __restrict__ out) {
    int g = blockIdx.x;
    int f = threadIdx.x;
    __shared__ float gh[HID];
    __shared__ float comb[2 * HID];

    float a = gb1[f];
#pragma unroll
    for (int k = 0; k < GLOB_F; ++k) a += gf[g * GLOB_F + k] * gW1[k * HID + f];
    gh[f] = fmaxf(a, 0.0f);
    __syncthreads();

    float a2 = gb2[f];
#pragma unroll 8
    for (int k = 0; k < HID; ++k) a2 += gh[k] * gW2[k * HID + f];

    float c = cnt[g];
    comb[f] = pooled[g * HID + f] / fmaxf(c, 1.0f);
    comb[HID + f] = a2;
    __syncthreads();

    float a3 = cb1[f];
#pragma unroll 8
    for (int k = 0; k < 2 * HID; ++k) a3 += comb[k] * cW1[k * HID + f];
    a3 = fmaxf(a3, 0.0f);

    float prod = a3 * cW2[f];
#pragma unroll
    for (int off = 32; off > 0; off >>= 1) prod += __shfl_down(prod, off);
    if (f == 0) out[g] = prod + cb2[0];
}

extern "C" void kernel_launch(void* const* d_in, const int* in_sizes, int n_in,
                              void* d_out, int out_size, void* d_ws, size_t ws_size,
                              hipStream_t stream) {
    const float* x     = (const float*)d_in[0];
    const int*   ei    = (const int*)d_in[1];
    const int*   batch = (const int*)d_in[2];
    const float* gf    = (const float*)d_in[3];
    const float* W1    = (const float*)d_in[4];
    const float* b1    = (const float*)d_in[5];
    const float* W2    = (const float*)d_in[6];
    const float* b2    = (const float*)d_in[7];
    const float* gW1   = (const float*)d_in[8];
    const float* gb1   = (const float*)d_in[9];
    const float* gW2   = (const float*)d_in[10];
    const float* gb2   = (const float*)d_in[11];
    const float* cW1   = (const float*)d_in[12];
    const float* cb1   = (const float*)d_in[13];
    const float* cW2   = (const float*)d_in[14];
    const float* cb2   = (const float*)d_in[15];
    float* out = (float*)d_out;

    const int* src = ei;
    const int* dst = ei + N_EDGES;

    // workspace layout
    char* w = (char*)d_ws;
    half_t* Hs      = (half_t*)w; w += (size_t)N_NODES * HID * sizeof(half_t);  // 12.8 MB
    float*  bufB    = (float*)w;  w += (size_t)N_NODES * HID * sizeof(float);   // 25.6 MB
    int*    indeg   = (int*)w;    w += (size_t)N_NODES * sizeof(int);
    float*  dinv    = (float*)w;  w += (size_t)N_NODES * sizeof(float);
    int*    rowoff  = (int*)w;    w += (size_t)(N_NODES + 1) * sizeof(int);
    int*    cursor  = (int*)w;    w += (size_t)N_NODES * sizeof(int);
    int*    csrc    = (int*)w;    w += (size_t)N_EDGES * sizeof(int);
    int*    blocksum= (int*)w;    w += (size_t)SCAN_NB * sizeof(int);
    float*  pooled  = (float*)w;  w += (size_t)N_GRAPHS * HID * sizeof(float);
    float*  cnt     = (float*)w;  w += (size_t)N_GRAPHS * sizeof(float);

    const int BT = 256;

    // ---- CSR build ----
    hipMemsetAsync(indeg, 0, (size_t)N_NODES * sizeof(int), stream);
    k_indeg<<<(N_EDGES / 4 + BT - 1) / BT, BT, 0, stream>>>(dst, indeg, N_EDGES);
    k_scan1<<<SCAN_NB, BT, 0, stream>>>(indeg, blocksum, N_NODES);
    k_scan2<<<1, 128, 0, stream>>>(blocksum, SCAN_NB);
    k_scan3<<<SCAN_NB, BT, 0, stream>>>(indeg, blocksum, rowoff, cursor, dinv, N_NODES);
    k_bucket<<<(N_EDGES / 4 + BT - 1) / BT, BT, 0, stream>>>(src, dst, cursor, csrc, N_EDGES);

    // ---- conv1 ----
    k_mm<NODE_F><<<(N_NODES + 3) / 4, BT, 0, stream>>>(x, W1, dinv, Hs, N_NODES);
    k_gather<1, 0><<<(N_NODES + 3) / 4, BT, 0, stream>>>(Hs, rowoff, csrc, dinv, b1,
                                                         bufB, nullptr, nullptr, nullptr, N_NODES);

    // ---- conv2 + mean-pool accumulation ----
    k_mm<HID><<<(N_NODES + 3) / 4, BT, 0, stream>>>(bufB, W2, dinv, Hs, N_NODES);
    hipMemsetAsync(pooled, 0, (size_t)(N_GRAPHS * HID + N_GRAPHS) * sizeof(float), stream);
    k_gather<0, 1><<<(N_NODES + 3) / 4, BT, 0, stream>>>(Hs, rowoff, csrc, dinv, b2,
                                                         nullptr, batch, pooled, cnt, N_NODES);

    // ---- MLP head ----
    k_head<<<N_GRAPHS, HID, 0, stream>>>(pooled, cnt, gf, gW1, gb1, gW2, gb2,
                                         cW1, cb1, cW2, cb2, out);
}

// Round 5
// 466.409 us; speedup vs baseline: 1.6106x; 1.6106x over previous
//
#include <hip/hip_runtime.h>

#define N_NODES  100000
#define N_EDGES  1600000
#define N_GRAPHS 1024
#define NODE_F   100
#define HID      64
#define GLOB_F   3

#define SCAN_CHUNK 1024
#define SCAN_NB    ((N_NODES + SCAN_CHUNK - 1) / SCAN_CHUNK)   // 98

typedef _Float16 half_t;
typedef __attribute__((ext_vector_type(8))) _Float16 half8;

// ---------------- degree (4 edges/thread, int4 loads) ----------------
__global__ void k_indeg(const int* __restrict__ dst, int* __restrict__ indeg, int E) {
    int i = (blockIdx.x * blockDim.x + threadIdx.x) * 4;
    if (i + 4 <= E) {
        int4 d = *reinterpret_cast<const int4*>(dst + i);
        atomicAdd(&indeg[d.x], 1);
        atomicAdd(&indeg[d.y], 1);
        atomicAdd(&indeg[d.z], 1);
        atomicAdd(&indeg[d.w], 1);
    } else {
        for (int j = i; j < E; ++j) atomicAdd(&indeg[dst[j]], 1);
    }
}

// ---------------- multi-block exclusive scan ----------------
__global__ void k_scan1(const int* __restrict__ indeg, int* __restrict__ blocksum, int N) {
    __shared__ int red[256];
    int t = threadIdx.x;
    int base = blockIdx.x * SCAN_CHUNK + t * 4;
    int s = 0;
#pragma unroll
    for (int j = 0; j < 4; ++j) { int i = base + j; if (i < N) s += indeg[i]; }
    red[t] = s;
    __syncthreads();
    for (int off = 128; off > 0; off >>= 1) {
        if (t < off) red[t] += red[t + off];
        __syncthreads();
    }
    if (t == 0) blocksum[blockIdx.x] = red[0];
}

__global__ void k_scan2(int* __restrict__ blocksum, int NB) {
    __shared__ int sh[128];
    int t = threadIdx.x;
    int v = (t < NB) ? blocksum[t] : 0;
    sh[t] = v;
    __syncthreads();
    for (int off = 1; off < 128; off <<= 1) {
        int o = (t >= off) ? sh[t - off] : 0;
        __syncthreads();
        sh[t] += o;
        __syncthreads();
    }
    if (t < NB) blocksum[t] = sh[t] - v;   // exclusive
}

__global__ void k_scan3(const int* __restrict__ indeg, const int* __restrict__ blocksum,
                        int* __restrict__ rowoff, int* __restrict__ cursor,
                        float* __restrict__ dinv, int N) {
    __shared__ int sh[256];
    int t = threadIdx.x;
    int base = blockIdx.x * SCAN_CHUNK + t * 4;
    int loc[4];
    int s = 0;
#pragma unroll
    for (int j = 0; j < 4; ++j) {
        int i = base + j;
        loc[j] = (i < N) ? indeg[i] : 0;
        s += loc[j];
    }
    sh[t] = s;
    __syncthreads();
    for (int off = 1; off < 256; off <<= 1) {
        int o = (t >= off) ? sh[t - off] : 0;
        __syncthreads();
        sh[t] += o;
        __syncthreads();
    }
    int run = blocksum[blockIdx.x] + sh[t] - s;
#pragma unroll
    for (int j = 0; j < 4; ++j) {
        int i = base + j;
        if (i < N) {
            rowoff[i] = run;
            cursor[i] = run;
            dinv[i] = 1.0f / sqrtf((float)(1 + loc[j]));
            run += loc[j];
            if (i == N - 1) rowoff[N] = run;
        }
    }
}

// ---------------- bucket edges by dst (4 edges/thread) ----------------
__global__ void k_bucket(const int* __restrict__ src, const int* __restrict__ dst,
                         int* __restrict__ cursor, int* __restrict__ csrc, int E) {
    int i = (blockIdx.x * blockDim.x + threadIdx.x) * 4;
    if (i + 4 <= E) {
        int4 s = *reinterpret_cast<const int4*>(src + i);
        int4 d = *reinterpret_cast<const int4*>(dst + i);
        int p;
        p = atomicAdd(&cursor[d.x], 1); csrc[p] = s.x;
        p = atomicAdd(&cursor[d.y], 1); csrc[p] = s.y;
        p = atomicAdd(&cursor[d.z], 1); csrc[p] = s.z;
        p = atomicAdd(&cursor[d.w], 1); csrc[p] = s.w;
    } else {
        for (int j = i; j < E; ++j) {
            int p = atomicAdd(&cursor[dst[j]], 1);
            csrc[p] = src[j];
        }
    }
}

// ---------------- dense MM: Y[r,c] = half((X[r,:]@W[:,c]) * dinv[r]) ----------------
template <int K>
__global__ void k_mm(const float* __restrict__ X, const float* __restrict__ W,
                     const float* __restrict__ dinv, half_t* __restrict__ Y, int N) {
    __shared__ float Ws[K * HID];
    __shared__ float Xs[4][K];
    int tid = threadIdx.x;
    for (int i = tid; i < K * HID; i += 256) Ws[i] = W[i];
    int row0 = blockIdx.x * 4;
    for (int i = tid; i < 4 * K; i += 256) {
        int r = row0 + i / K;
        Xs[i / K][i % K] = (r < N) ? X[(long long)r * K + (i % K)] : 0.0f;
    }
    __syncthreads();
    int ty = tid >> 6;
    int c  = tid & 63;
    int r  = row0 + ty;
    if (r < N) {
        float acc = 0.0f;
#pragma unroll
        for (int k = 0; k < K; ++k) acc += Xs[ty][k] * Ws[k * HID + c];
        Y[(long long)r * HID + c] = (half_t)(acc * dinv[r]);
    }
}

// ---------------- per-dst gather, fp16 payload -> dense f32 out ----------------
// 1 wave per dst node. Lane = 8*g + l: edge slot g (0..7), feature octet l (0..7).
template <int RELU>
__global__ void k_gather(const half_t* __restrict__ Hs, const int* __restrict__ rowoff,
                         const int* __restrict__ csrc, const float* __restrict__ dinv,
                         const float* __restrict__ b, float* __restrict__ outbuf, int N) {
    int tid = threadIdx.x;
    int d = blockIdx.x * 4 + (tid >> 6);
    if (d >= N) return;
    int lane = tid & 63;
    int g = lane >> 3;
    int l = lane & 7;
    int lo = rowoff[d], hi = rowoff[d + 1];

    float acc[8] = {0, 0, 0, 0, 0, 0, 0, 0};

    int e = lo;
    for (; e + 16 <= hi; e += 16) {
        int s0 = csrc[e + g];
        int s1 = csrc[e + 8 + g];
        half8 h0 = *reinterpret_cast<const half8*>(Hs + (size_t)s0 * HID + l * 8);
        half8 h1 = *reinterpret_cast<const half8*>(Hs + (size_t)s1 * HID + l * 8);
#pragma unroll
        for (int j = 0; j < 8; ++j) acc[j] += (float)h0[j];
#pragma unroll
        for (int j = 0; j < 8; ++j) acc[j] += (float)h1[j];
    }
    for (; e < hi; e += 8) {
        int ee = e + g;
        if (ee < hi) {
            int s = csrc[ee];
            half8 hv = *reinterpret_cast<const half8*>(Hs + (size_t)s * HID + l * 8);
#pragma unroll
            for (int j = 0; j < 8; ++j) acc[j] += (float)hv[j];
        }
    }
    if (g == 0) {   // self-loop row
        half8 hv = *reinterpret_cast<const half8*>(Hs + (size_t)d * HID + l * 8);
#pragma unroll
        for (int j = 0; j < 8; ++j) acc[j] += (float)hv[j];
    }
#pragma unroll
    for (int off = 8; off <= 32; off <<= 1) {
#pragma unroll
        for (int j = 0; j < 8; ++j) acc[j] += __shfl_xor(acc[j], off);
    }

    if (g == 0) {
        float dd = dinv[d];
        float v[8];
#pragma unroll
        for (int j = 0; j < 8; ++j) {
            v[j] = acc[j] * dd + b[l * 8 + j];
            if (RELU) v[j] = fmaxf(v[j], 0.0f);
        }
        float4* o = reinterpret_cast<float4*>(outbuf + (size_t)d * HID + l * 8);
        o[0] = make_float4(v[0], v[1], v[2], v[3]);
        o[1] = make_float4(v[4], v[5], v[6], v[7]);
    }
}

// ---------------- segment mean-pool: one block per graph, batch sorted ----------------
__global__ void k_pool(const float* __restrict__ H, const int* __restrict__ batch,
                       float* __restrict__ pooled, int N) {
    int g = blockIdx.x;
    __shared__ int sh_lo, sh_hi;
    __shared__ float red[4][HID];
    if (threadIdx.x == 0) {
        int lo = 0, hi = N;
        while (lo < hi) { int m = (lo + hi) >> 1; if (batch[m] < g) lo = m + 1; else hi = m; }
        sh_lo = lo;
        int lo2 = lo, hi2 = N;
        while (lo2 < hi2) { int m = (lo2 + hi2) >> 1; if (batch[m] < g + 1) lo2 = m + 1; else hi2 = m; }
        sh_hi = lo2;
    }
    __syncthreads();
    int lo = sh_lo, hi = sh_hi;
    int wave = threadIdx.x >> 6, lane = threadIdx.x & 63;
    float acc = 0.0f;
    for (int i = lo + wave; i < hi; i += 4)
        acc += H[(size_t)i * HID + lane];
    red[wave][lane] = acc;
    __syncthreads();
    if (wave == 0) {
        float s = red[0][lane] + red[1][lane] + red[2][lane] + red[3][lane];
        int c = hi - lo;
        pooled[g * HID + lane] = s / (float)(c > 0 ? c : 1);
    }
}

// ---------------- MLP head: one wave per graph ----------------
__global__ void k_head(const float* __restrict__ pooled,
                       const float* __restrict__ gf,
                       const float* __restrict__ gW1, const float* __restrict__ gb1,
                       const float* __restrict__ gW2, const float* __restrict__ gb2,
                       const float* __restrict__ cW1, const float* __restrict__ cb1,
                       const float* __restrict__ cW2, const float* __restrict__ cb2,
                       float* __restrict__ out) {
    int g = blockIdx.x;
    int f = threadIdx.x;
    __shared__ float gh[HID];
    __shared__ float comb[2 * HID];

    float a = gb1[f];
#pragma unroll
    for (int k = 0; k < GLOB_F; ++k) a += gf[g * GLOB_F + k] * gW1[k * HID + f];
    gh[f] = fmaxf(a, 0.0f);
    __syncthreads();

    float a2 = gb2[f];
#pragma unroll 8
    for (int k = 0; k < HID; ++k) a2 += gh[k] * gW2[k * HID + f];

    comb[f] = pooled[g * HID + f];
    comb[HID + f] = a2;
    __syncthreads();

    float a3 = cb1[f];
#pragma unroll 8
    for (int k = 0; k < 2 * HID; ++k) a3 += comb[k] * cW1[k * HID + f];
    a3 = fmaxf(a3, 0.0f);

    float prod = a3 * cW2[f];
#pragma unroll
    for (int off = 32; off > 0; off >>= 1) prod += __shfl_down(prod, off);
    if (f == 0) out[g] = prod + cb2[0];
}

extern "C" void kernel_launch(void* const* d_in, const int* in_sizes, int n_in,
                              void* d_out, int out_size, void* d_ws, size_t ws_size,
                              hipStream_t stream) {
    const float* x     = (const float*)d_in[0];
    const int*   ei    = (const int*)d_in[1];
    const int*   batch = (const int*)d_in[2];
    const float* gf    = (const float*)d_in[3];
    const float* W1    = (const float*)d_in[4];
    const float* b1    = (const float*)d_in[5];
    const float* W2    = (const float*)d_in[6];
    const float* b2    = (const float*)d_in[7];
    const float* gW1   = (const float*)d_in[8];
    const float* gb1   = (const float*)d_in[9];
    const float* gW2   = (const float*)d_in[10];
    const float* gb2   = (const float*)d_in[11];
    const float* cW1   = (const float*)d_in[12];
    const float* cb1   = (const float*)d_in[13];
    const float* cW2   = (const float*)d_in[14];
    const float* cb2   = (const float*)d_in[15];
    float* out = (float*)d_out;

    const int* src = ei;
    const int* dst = ei + N_EDGES;

    // workspace layout
    char* w = (char*)d_ws;
    half_t* Hs      = (half_t*)w; w += (size_t)N_NODES * HID * sizeof(half_t);  // 12.8 MB
    float*  bufB    = (float*)w;  w += (size_t)N_NODES * HID * sizeof(float);   // 25.6 MB
    int*    indeg   = (int*)w;    w += (size_t)N_NODES * sizeof(int);
    float*  dinv    = (float*)w;  w += (size_t)N_NODES * sizeof(float);
    int*    rowoff  = (int*)w;    w += (size_t)(N_NODES + 1) * sizeof(int);
    int*    cursor  = (int*)w;    w += (size_t)N_NODES * sizeof(int);
    int*    csrc    = (int*)w;    w += (size_t)N_EDGES * sizeof(int);
    int*    blocksum= (int*)w;    w += (size_t)SCAN_NB * sizeof(int);
    float*  pooled  = (float*)w;  w += (size_t)N_GRAPHS * HID * sizeof(float);

    const int BT = 256;

    // ---- CSR build ----
    hipMemsetAsync(indeg, 0, (size_t)N_NODES * sizeof(int), stream);
    k_indeg<<<(N_EDGES / 4 + BT - 1) / BT, BT, 0, stream>>>(dst, indeg, N_EDGES);
    k_scan1<<<SCAN_NB, BT, 0, stream>>>(indeg, blocksum, N_NODES);
    k_scan2<<<1, 128, 0, stream>>>(blocksum, SCAN_NB);
    k_scan3<<<SCAN_NB, BT, 0, stream>>>(indeg, blocksum, rowoff, cursor, dinv, N_NODES);
    k_bucket<<<(N_EDGES / 4 + BT - 1) / BT, BT, 0, stream>>>(src, dst, cursor, csrc, N_EDGES);

    // ---- conv1 ----
    k_mm<NODE_F><<<(N_NODES + 3) / 4, BT, 0, stream>>>(x, W1, dinv, Hs, N_NODES);
    k_gather<1><<<(N_NODES + 3) / 4, BT, 0, stream>>>(Hs, rowoff, csrc, dinv, b1, bufB, N_NODES);

    // ---- conv2 (dense out, no atomics) ----
    k_mm<HID><<<(N_NODES + 3) / 4, BT, 0, stream>>>(bufB, W2, dinv, Hs, N_NODES);
    k_gather<0><<<(N_NODES + 3) / 4, BT, 0, stream>>>(Hs, rowoff, csrc, dinv, b2, bufB, N_NODES);

    // ---- segment mean-pool (batch sorted, zero atomics) ----
    k_pool<<<N_GRAPHS, BT, 0, stream>>>(bufB, batch, pooled, N_NODES);

    // ---- MLP head ----
    k_head<<<N_GRAPHS, HID, 0, stream>>>(pooled, gf, gW1, gb1, gW2, gb2,
                                         cW1, cb1, cW2, cb2, out);
}

// Round 6
// 418.768 us; speedup vs baseline: 1.7938x; 1.1138x over previous
//
#include <hip/hip_runtime.h>

#define N_NODES  100000
#define N_EDGES  1600000
#define N_GRAPHS 1024
#define NODE_F   100
#define HID      64
#define GLOB_F   3

#define SCAN_CHUNK 1024
#define SCAN_NB    ((N_NODES + SCAN_CHUNK - 1) / SCAN_CHUNK)   // 98

// dst-range partitioning for indeg/bucket (write-locality)
#define P_PART     8                      // partitions (node ranges)
#define W_PART     1024                   // blocks per partition
#define R_PART     ((N_NODES + P_PART - 1) / P_PART)           // 12500 nodes/partition
#define CHUNK_PART ((N_EDGES + W_PART - 1) / W_PART)           // 1563 edges/block

typedef _Float16 half_t;
typedef __attribute__((ext_vector_type(8))) _Float16 half8;

// ---------------- degree, partition-filtered (atomics confined to 50KB window) ----------------
__global__ void k_indeg(const int* __restrict__ dst, int* __restrict__ indeg, int E) {
    int p = blockIdx.x / W_PART;
    int w = blockIdx.x % W_PART;
    int lo_node = p * R_PART;
    int start = w * CHUNK_PART;
    int end = start + CHUNK_PART; if (end > E) end = E;
    for (int i = start + (int)threadIdx.x; i < end; i += 256) {
        int d = dst[i];
        if ((unsigned)(d - lo_node) < (unsigned)R_PART) atomicAdd(&indeg[d], 1);
    }
}

// ---------------- multi-block exclusive scan ----------------
__global__ void k_scan1(const int* __restrict__ indeg, int* __restrict__ blocksum, int N) {
    __shared__ int red[256];
    int t = threadIdx.x;
    int base = blockIdx.x * SCAN_CHUNK + t * 4;
    int s = 0;
#pragma unroll
    for (int j = 0; j < 4; ++j) { int i = base + j; if (i < N) s += indeg[i]; }
    red[t] = s;
    __syncthreads();
    for (int off = 128; off > 0; off >>= 1) {
        if (t < off) red[t] += red[t + off];
        __syncthreads();
    }
    if (t == 0) blocksum[blockIdx.x] = red[0];
}

__global__ void k_scan2(int* __restrict__ blocksum, int NB) {
    __shared__ int sh[128];
    int t = threadIdx.x;
    int v = (t < NB) ? blocksum[t] : 0;
    sh[t] = v;
    __syncthreads();
    for (int off = 1; off < 128; off <<= 1) {
        int o = (t >= off) ? sh[t - off] : 0;
        __syncthreads();
        sh[t] += o;
        __syncthreads();
    }
    if (t < NB) blocksum[t] = sh[t] - v;   // exclusive
}

__global__ void k_scan3(const int* __restrict__ indeg, const int* __restrict__ blocksum,
                        int* __restrict__ rowoff, int* __restrict__ cursor,
                        float* __restrict__ dinv, int N) {
    __shared__ int sh[256];
    int t = threadIdx.x;
    int base = blockIdx.x * SCAN_CHUNK + t * 4;
    int loc[4];
    int s = 0;
#pragma unroll
    for (int j = 0; j < 4; ++j) {
        int i = base + j;
        loc[j] = (i < N) ? indeg[i] : 0;
        s += loc[j];
    }
    sh[t] = s;
    __syncthreads();
    for (int off = 1; off < 256; off <<= 1) {
        int o = (t >= off) ? sh[t - off] : 0;
        __syncthreads();
        sh[t] += o;
        __syncthreads();
    }
    int run = blocksum[blockIdx.x] + sh[t] - s;
#pragma unroll
    for (int j = 0; j < 4; ++j) {
        int i = base + j;
        if (i < N) {
            rowoff[i] = run;
            cursor[i] = run;
            dinv[i] = 1.0f / sqrtf((float)(1 + loc[j]));
            run += loc[j];
            if (i == N - 1) rowoff[N] = run;
        }
    }
}

// ---------------- bucket, partition-filtered (cursor+csrc writes confined to ~800KB) ----------------
__global__ void k_bucket(const int* __restrict__ src, const int* __restrict__ dst,
                         int* __restrict__ cursor, int* __restrict__ csrc, int E) {
    int p = blockIdx.x / W_PART;
    int w = blockIdx.x % W_PART;
    int lo_node = p * R_PART;
    int start = w * CHUNK_PART;
    int end = start + CHUNK_PART; if (end > E) end = E;
    for (int i = start + (int)threadIdx.x; i < end; i += 256) {
        int d = dst[i];
        if ((unsigned)(d - lo_node) < (unsigned)R_PART) {
            int pos = atomicAdd(&cursor[d], 1);
            csrc[pos] = src[i];
        }
    }
}

// ---------------- dense MM: Y[r,c] = half((X[r,:]@W[:,c]) * dinv[r]) ----------------
template <int K>
__global__ void k_mm(const float* __restrict__ X, const float* __restrict__ W,
                     const float* __restrict__ dinv, half_t* __restrict__ Y, int N) {
    __shared__ float Ws[K * HID];
    __shared__ float Xs[4][K];
    int tid = threadIdx.x;
    for (int i = tid; i < K * HID; i += 256) Ws[i] = W[i];
    int row0 = blockIdx.x * 4;
    for (int i = tid; i < 4 * K; i += 256) {
        int r = row0 + i / K;
        Xs[i / K][i % K] = (r < N) ? X[(long long)r * K + (i % K)] : 0.0f;
    }
    __syncthreads();
    int ty = tid >> 6;
    int c  = tid & 63;
    int r  = row0 + ty;
    if (r < N) {
        float acc = 0.0f;
#pragma unroll
        for (int k = 0; k < K; ++k) acc += Xs[ty][k] * Ws[k * HID + c];
        Y[(long long)r * HID + c] = (half_t)(acc * dinv[r]);
    }
}

// ---------------- per-dst gather, fp16 payload -> dense f32 out ----------------
// 1 wave per dst node. Lane = 8*g + l: edge slot g (0..7), feature octet l (0..7).
template <int RELU>
__global__ void k_gather(const half_t* __restrict__ Hs, const int* __restrict__ rowoff,
                         const int* __restrict__ csrc, const float* __restrict__ dinv,
                         const float* __restrict__ b, float* __restrict__ outbuf, int N) {
    int tid = threadIdx.x;
    int d = blockIdx.x * 4 + (tid >> 6);
    if (d >= N) return;
    int lane = tid & 63;
    int g = lane >> 3;
    int l = lane & 7;
    int lo = rowoff[d], hi = rowoff[d + 1];

    float acc[8] = {0, 0, 0, 0, 0, 0, 0, 0};

    int e = lo;
    for (; e + 16 <= hi; e += 16) {
        int s0 = csrc[e + g];
        int s1 = csrc[e + 8 + g];
        half8 h0 = *reinterpret_cast<const half8*>(Hs + (size_t)s0 * HID + l * 8);
        half8 h1 = *reinterpret_cast<const half8*>(Hs + (size_t)s1 * HID + l * 8);
#pragma unroll
        for (int j = 0; j < 8; ++j) acc[j] += (float)h0[j];
#pragma unroll
        for (int j = 0; j < 8; ++j) acc[j] += (float)h1[j];
    }
    for (; e < hi; e += 8) {
        int ee = e + g;
        if (ee < hi) {
            int s = csrc[ee];
            half8 hv = *reinterpret_cast<const half8*>(Hs + (size_t)s * HID + l * 8);
#pragma unroll
            for (int j = 0; j < 8; ++j) acc[j] += (float)hv[j];
        }
    }
    if (g == 0) {   // self-loop row
        half8 hv = *reinterpret_cast<const half8*>(Hs + (size_t)d * HID + l * 8);
#pragma unroll
        for (int j = 0; j < 8; ++j) acc[j] += (float)hv[j];
    }
#pragma unroll
    for (int off = 8; off <= 32; off <<= 1) {
#pragma unroll
        for (int j = 0; j < 8; ++j) acc[j] += __shfl_xor(acc[j], off);
    }

    if (g == 0) {
        float dd = dinv[d];
        float v[8];
#pragma unroll
        for (int j = 0; j < 8; ++j) {
            v[j] = acc[j] * dd + b[l * 8 + j];
            if (RELU) v[j] = fmaxf(v[j], 0.0f);
        }
        float4* o = reinterpret_cast<float4*>(outbuf + (size_t)d * HID + l * 8);
        o[0] = make_float4(v[0], v[1], v[2], v[3]);
        o[1] = make_float4(v[4], v[5], v[6], v[7]);
    }
}

// ---------------- segment mean-pool: one block per graph, batch sorted ----------------
__global__ void k_pool(const float* __restrict__ H, const int* __restrict__ batch,
                       float* __restrict__ pooled, int N) {
    int g = blockIdx.x;
    __shared__ int sh_lo, sh_hi;
    __shared__ float red[4][HID];
    if (threadIdx.x == 0) {
        int lo = 0, hi = N;
        while (lo < hi) { int m = (lo + hi) >> 1; if (batch[m] < g) lo = m + 1; else hi = m; }
        sh_lo = lo;
        int lo2 = lo, hi2 = N;
        while (lo2 < hi2) { int m = (lo2 + hi2) >> 1; if (batch[m] < g + 1) lo2 = m + 1; else hi2 = m; }
        sh_hi = lo2;
    }
    __syncthreads();
    int lo = sh_lo, hi = sh_hi;
    int wave = threadIdx.x >> 6, lane = threadIdx.x & 63;
    float acc = 0.0f;
    for (int i = lo + wave; i < hi; i += 4)
        acc += H[(size_t)i * HID + lane];
    red[wave][lane] = acc;
    __syncthreads();
    if (wave == 0) {
        float s = red[0][lane] + red[1][lane] + red[2][lane] + red[3][lane];
        int c = hi - lo;
        pooled[g * HID + lane] = s / (float)(c > 0 ? c : 1);
    }
}

// ---------------- MLP head: one wave per graph ----------------
__global__ void k_head(const float* __restrict__ pooled,
                       const float* __restrict__ gf,
                       const float* __restrict__ gW1, const float* __restrict__ gb1,
                       const float* __restrict__ gW2, const float* __restrict__ gb2,
                       const float* __restrict__ cW1, const float* __restrict__ cb1,
                       const float* __restrict__ cW2, const float* __restrict__ cb2,
                       float* __restrict__ out) {
    int g = blockIdx.x;
    int f = threadIdx.x;
    __shared__ float gh[HID];
    __shared__ float comb[2 * HID];

    float a = gb1[f];
#pragma unroll
    for (int k = 0; k < GLOB_F; ++k) a += gf[g * GLOB_F + k] * gW1[k * HID + f];
    gh[f] = fmaxf(a, 0.0f);
    __syncthreads();

    float a2 = gb2[f];
#pragma unroll 8
    for (int k = 0; k < HID; ++k) a2 += gh[k] * gW2[k * HID + f];

    comb[f] = pooled[g * HID + f];
    comb[HID + f] = a2;
    __syncthreads();

    float a3 = cb1[f];
#pragma unroll 8
    for (int k = 0; k < 2 * HID; ++k) a3 += comb[k] * cW1[k * HID + f];
    a3 = fmaxf(a3, 0.0f);

    float prod = a3 * cW2[f];
#pragma unroll
    for (int off = 32; off > 0; off >>= 1) prod += __shfl_down(prod, off);
    if (f == 0) out[g] = prod + cb2[0];
}

extern "C" void kernel_launch(void* const* d_in, const int* in_sizes, int n_in,
                              void* d_out, int out_size, void* d_ws, size_t ws_size,
                              hipStream_t stream) {
    const float* x     = (const float*)d_in[0];
    const int*   ei    = (const int*)d_in[1];
    const int*   batch = (const int*)d_in[2];
    const float* gf    = (const float*)d_in[3];
    const float* W1    = (const float*)d_in[4];
    const float* b1    = (const float*)d_in[5];
    const float* W2    = (const float*)d_in[6];
    const float* b2    = (const float*)d_in[7];
    const float* gW1   = (const float*)d_in[8];
    const float* gb1   = (const float*)d_in[9];
    const float* gW2   = (const float*)d_in[10];
    const float* gb2   = (const float*)d_in[11];
    const float* cW1   = (const float*)d_in[12];
    const float* cb1   = (const float*)d_in[13];
    const float* cW2   = (const float*)d_in[14];
    const float* cb2   = (const float*)d_in[15];
    float* out = (float*)d_out;

    const int* src = ei;
    const int* dst = ei + N_EDGES;

    // workspace layout
    char* w = (char*)d_ws;
    half_t* Hs      = (half_t*)w; w += (size_t)N_NODES * HID * sizeof(half_t);  // 12.8 MB
    float*  bufB    = (float*)w;  w += (size_t)N_NODES * HID * sizeof(float);   // 25.6 MB
    int*    indeg   = (int*)w;    w += (size_t)N_NODES * sizeof(int);
    float*  dinv    = (float*)w;  w += (size_t)N_NODES * sizeof(float);
    int*    rowoff  = (int*)w;    w += (size_t)(N_NODES + 1) * sizeof(int);
    int*    cursor  = (int*)w;    w += (size_t)N_NODES * sizeof(int);
    int*    csrc    = (int*)w;    w += (size_t)N_EDGES * sizeof(int);
    int*    blocksum= (int*)w;    w += (size_t)SCAN_NB * sizeof(int);
    float*  pooled  = (float*)w;  w += (size_t)N_GRAPHS * HID * sizeof(float);

    const int BT = 256;

    // ---- CSR build (partition-filtered atomics for write locality) ----
    hipMemsetAsync(indeg, 0, (size_t)N_NODES * sizeof(int), stream);
    k_indeg<<<P_PART * W_PART, BT, 0, stream>>>(dst, indeg, N_EDGES);
    k_scan1<<<SCAN_NB, BT, 0, stream>>>(indeg, blocksum, N_NODES);
    k_scan2<<<1, 128, 0, stream>>>(blocksum, SCAN_NB);
    k_scan3<<<SCAN_NB, BT, 0, stream>>>(indeg, blocksum, rowoff, cursor, dinv, N_NODES);
    k_bucket<<<P_PART * W_PART, BT, 0, stream>>>(src, dst, cursor, csrc, N_EDGES);

    // ---- conv1 ----
    k_mm<NODE_F><<<(N_NODES + 3) / 4, BT, 0, stream>>>(x, W1, dinv, Hs, N_NODES);
    k_gather<1><<<(N_NODES + 3) / 4, BT, 0, stream>>>(Hs, rowoff, csrc, dinv, b1, bufB, N_NODES);

    // ---- conv2 (dense out, no atomics) ----
    k_mm<HID><<<(N_NODES + 3) / 4, BT, 0, stream>>>(bufB, W2, dinv, Hs, N_NODES);
    k_gather<0><<<(N_NODES + 3) / 4, BT, 0, stream>>>(Hs, rowoff, csrc, dinv, b2, bufB, N_NODES);

    // ---- segment mean-pool (batch sorted, zero atomics) ----
    k_pool<<<N_GRAPHS, BT, 0, stream>>>(bufB, batch, pooled, N_NODES);

    // ---- MLP head ----
    k_head<<<N_GRAPHS, HID, 0, stream>>>(pooled, gf, gW1, gb1, gW2, gb2,
                                         cW1, cb1, cW2, cb2, out);
}

// Round 7
// 351.269 us; speedup vs baseline: 2.1385x; 1.1922x over previous
//
#include <hip/hip_runtime.h>

#define N_NODES  100000
#define N_EDGES  1600000
#define N_GRAPHS 1024
#define NODE_F   100
#define HID      64
#define GLOB_F   3

#define SCAN_CHUNK 1024
#define SCAN_NB    ((N_NODES + SCAN_CHUNK - 1) / SCAN_CHUNK)   // 98

// dst-range partitioning for indeg/bucket (write-locality)
#define P_PART     8
#define W_PART     1024
#define R_PART     ((N_NODES + P_PART - 1) / P_PART)           // 12500 nodes/partition
#define CHUNK_PART ((N_EDGES + W_PART - 1) / W_PART)           // 1563 edges/block

typedef _Float16 half_t;
typedef __attribute__((ext_vector_type(8))) _Float16 half8;

// ---------------- degree, partition-filtered ----------------
__global__ void k_indeg(const int* __restrict__ dst, int* __restrict__ indeg, int E) {
    int p = blockIdx.x / W_PART;
    int w = blockIdx.x % W_PART;
    int lo_node = p * R_PART;
    int start = w * CHUNK_PART;
    int end = start + CHUNK_PART; if (end > E) end = E;
    for (int i = start + (int)threadIdx.x; i < end; i += 256) {
        int d = dst[i];
        if ((unsigned)(d - lo_node) < (unsigned)R_PART) atomicAdd(&indeg[d], 1);
    }
}

// ---------------- multi-block exclusive scan ----------------
__global__ void k_scan1(const int* __restrict__ indeg, int* __restrict__ blocksum, int N) {
    __shared__ int red[256];
    int t = threadIdx.x;
    int base = blockIdx.x * SCAN_CHUNK + t * 4;
    int s = 0;
#pragma unroll
    for (int j = 0; j < 4; ++j) { int i = base + j; if (i < N) s += indeg[i]; }
    red[t] = s;
    __syncthreads();
    for (int off = 128; off > 0; off >>= 1) {
        if (t < off) red[t] += red[t + off];
        __syncthreads();
    }
    if (t == 0) blocksum[blockIdx.x] = red[0];
}

__global__ void k_scan2(int* __restrict__ blocksum, int NB) {
    __shared__ int sh[128];
    int t = threadIdx.x;
    int v = (t < NB) ? blocksum[t] : 0;
    sh[t] = v;
    __syncthreads();
    for (int off = 1; off < 128; off <<= 1) {
        int o = (t >= off) ? sh[t - off] : 0;
        __syncthreads();
        sh[t] += o;
        __syncthreads();
    }
    if (t < NB) blocksum[t] = sh[t] - v;   // exclusive
}

__global__ void k_scan3(const int* __restrict__ indeg, const int* __restrict__ blocksum,
                        int* __restrict__ rowoff, int* __restrict__ cursor,
                        float* __restrict__ dinv, int N) {
    __shared__ int sh[256];
    int t = threadIdx.x;
    int base = blockIdx.x * SCAN_CHUNK + t * 4;
    int loc[4];
    int s = 0;
#pragma unroll
    for (int j = 0; j < 4; ++j) {
        int i = base + j;
        loc[j] = (i < N) ? indeg[i] : 0;
        s += loc[j];
    }
    sh[t] = s;
    __syncthreads();
    for (int off = 1; off < 256; off <<= 1) {
        int o = (t >= off) ? sh[t - off] : 0;
        __syncthreads();
        sh[t] += o;
        __syncthreads();
    }
    int run = blocksum[blockIdx.x] + sh[t] - s;
#pragma unroll
    for (int j = 0; j < 4; ++j) {
        int i = base + j;
        if (i < N) {
            rowoff[i] = run;
            cursor[i] = run;
            dinv[i] = 1.0f / sqrtf((float)(1 + loc[j]));
            run += loc[j];
            if (i == N - 1) rowoff[N] = run;
        }
    }
}

// ---------------- bucket, partition-filtered ----------------
__global__ void k_bucket(const int* __restrict__ src, const int* __restrict__ dst,
                         int* __restrict__ cursor, int* __restrict__ csrc, int E) {
    int p = blockIdx.x / W_PART;
    int w = blockIdx.x % W_PART;
    int lo_node = p * R_PART;
    int start = w * CHUNK_PART;
    int end = start + CHUNK_PART; if (end > E) end = E;
    for (int i = start + (int)threadIdx.x; i < end; i += 256) {
        int d = dst[i];
        if ((unsigned)(d - lo_node) < (unsigned)R_PART) {
            int pos = atomicAdd(&cursor[d], 1);
            csrc[pos] = src[i];
        }
    }
}

// ---------------- dense MM: W column in VGPRs, X broadcast from LDS ----------------
// 256 threads = 4 waves; 16 rows/block (100000 % 16 == 0). Lane owns column `lane`.
template <int K>
__launch_bounds__(256, 3)
__global__ void k_mm(const float* __restrict__ X, const float* __restrict__ W,
                     const float* __restrict__ dinv, half_t* __restrict__ Y, int N) {
    __shared__ float Xs[16 * K];          // contiguous 16-row chunk of X
    int tid = threadIdx.x;
    int row0 = blockIdx.x * 16;

    // stage 16 rows of X (flat float4 copy; X rows are 16B-aligned since K%4==0)
    const float4* Xg = reinterpret_cast<const float4*>(X + (size_t)row0 * K);
    float4* Xls = reinterpret_cast<float4*>(Xs);
    for (int i = tid; i < 16 * K / 4; i += 256) Xls[i] = Xg[i];

    int lane = tid & 63;
    int wv = tid >> 6;

    // W column `lane` into registers (static unrolled indices -> stays in VGPRs)
    float Wr[K];
#pragma unroll
    for (int k = 0; k < K; ++k) Wr[k] = W[k * HID + lane];
    __syncthreads();

#pragma unroll
    for (int rr = 0; rr < 4; ++rr) {
        int r = row0 + wv * 4 + rr;
        const float4* xrow = reinterpret_cast<const float4*>(&Xs[(wv * 4 + rr) * K]);
        float acc0 = 0.f, acc1 = 0.f, acc2 = 0.f, acc3 = 0.f;
#pragma unroll
        for (int k4 = 0; k4 < K / 4; ++k4) {
            float4 xv = xrow[k4];          // broadcast read: conflict-free
            acc0 += xv.x * Wr[k4 * 4 + 0];
            acc1 += xv.y * Wr[k4 * 4 + 1];
            acc2 += xv.z * Wr[k4 * 4 + 2];
            acc3 += xv.w * Wr[k4 * 4 + 3];
        }
        float acc = (acc0 + acc1) + (acc2 + acc3);
        Y[(size_t)r * HID + lane] = (half_t)(acc * dinv[r]);
    }
}

// ---------------- per-dst gather, fp16 payload -> dense f32 out ----------------
template <int RELU>
__global__ void k_gather(const half_t* __restrict__ Hs, const int* __restrict__ rowoff,
                         const int* __restrict__ csrc, const float* __restrict__ dinv,
                         const float* __restrict__ b, float* __restrict__ outbuf, int N) {
    int tid = threadIdx.x;
    int d = blockIdx.x * 4 + (tid >> 6);
    if (d >= N) return;
    int lane = tid & 63;
    int g = lane >> 3;
    int l = lane & 7;
    int lo = rowoff[d], hi = rowoff[d + 1];

    float acc[8] = {0, 0, 0, 0, 0, 0, 0, 0};

    int e = lo;
    for (; e + 16 <= hi; e += 16) {
        int s0 = csrc[e + g];
        int s1 = csrc[e + 8 + g];
        half8 h0 = *reinterpret_cast<const half8*>(Hs + (size_t)s0 * HID + l * 8);
        half8 h1 = *reinterpret_cast<const half8*>(Hs + (size_t)s1 * HID + l * 8);
#pragma unroll
        for (int j = 0; j < 8; ++j) acc[j] += (float)h0[j];
#pragma unroll
        for (int j = 0; j < 8; ++j) acc[j] += (float)h1[j];
    }
    for (; e < hi; e += 8) {
        int ee = e + g;
        if (ee < hi) {
            int s = csrc[ee];
            half8 hv = *reinterpret_cast<const half8*>(Hs + (size_t)s * HID + l * 8);
#pragma unroll
            for (int j = 0; j < 8; ++j) acc[j] += (float)hv[j];
        }
    }
    if (g == 0) {   // self-loop row
        half8 hv = *reinterpret_cast<const half8*>(Hs + (size_t)d * HID + l * 8);
#pragma unroll
        for (int j = 0; j < 8; ++j) acc[j] += (float)hv[j];
    }
#pragma unroll
    for (int off = 8; off <= 32; off <<= 1) {
#pragma unroll
        for (int j = 0; j < 8; ++j) acc[j] += __shfl_xor(acc[j], off);
    }

    if (g == 0) {
        float dd = dinv[d];
        float v[8];
#pragma unroll
        for (int j = 0; j < 8; ++j) {
            v[j] = acc[j] * dd + b[l * 8 + j];
            if (RELU) v[j] = fmaxf(v[j], 0.0f);
        }
        float4* o = reinterpret_cast<float4*>(outbuf + (size_t)d * HID + l * 8);
        o[0] = make_float4(v[0], v[1], v[2], v[3]);
        o[1] = make_float4(v[4], v[5], v[6], v[7]);
    }
}

// ---------------- segment mean-pool: one block per graph, batch sorted ----------------
__global__ void k_pool(const float* __restrict__ H, const int* __restrict__ batch,
                       float* __restrict__ pooled, int N) {
    int g = blockIdx.x;
    __shared__ int sh_lo, sh_hi;
    __shared__ float red[4][HID];
    if (threadIdx.x == 0) {
        int lo = 0, hi = N;
        while (lo < hi) { int m = (lo + hi) >> 1; if (batch[m] < g) lo = m + 1; else hi = m; }
        sh_lo = lo;
        int lo2 = lo, hi2 = N;
        while (lo2 < hi2) { int m = (lo2 + hi2) >> 1; if (batch[m] < g + 1) lo2 = m + 1; else hi2 = m; }
        sh_hi = lo2;
    }
    __syncthreads();
    int lo = sh_lo, hi = sh_hi;
    int wave = threadIdx.x >> 6, lane = threadIdx.x & 63;
    float acc = 0.0f;
    for (int i = lo + wave; i < hi; i += 4)
        acc += H[(size_t)i * HID + lane];
    red[wave][lane] = acc;
    __syncthreads();
    if (wave == 0) {
        float s = red[0][lane] + red[1][lane] + red[2][lane] + red[3][lane];
        int c = hi - lo;
        pooled[g * HID + lane] = s / (float)(c > 0 ? c : 1);
    }
}

// ---------------- MLP head: one wave per graph ----------------
__global__ void k_head(const float* __restrict__ pooled,
                       const float* __restrict__ gf,
                       const float* __restrict__ gW1, const float* __restrict__ gb1,
                       const float* __restrict__ gW2, const float* __restrict__ gb2,
                       const float* __restrict__ cW1, const float* __restrict__ cb1,
                       const float* __restrict__ cW2, const float* __restrict__ cb2,
                       float* __restrict__ out) {
    int g = blockIdx.x;
    int f = threadIdx.x;
    __shared__ float gh[HID];
    __shared__ float comb[2 * HID];

    float a = gb1[f];
#pragma unroll
    for (int k = 0; k < GLOB_F; ++k) a += gf[g * GLOB_F + k] * gW1[k * HID + f];
    gh[f] = fmaxf(a, 0.0f);
    __syncthreads();

    float a2 = gb2[f];
#pragma unroll 8
    for (int k = 0; k < HID; ++k) a2 += gh[k] * gW2[k * HID + f];

    comb[f] = pooled[g * HID + f];
    comb[HID + f] = a2;
    __syncthreads();

    float a3 = cb1[f];
#pragma unroll 8
    for (int k = 0; k < 2 * HID; ++k) a3 += comb[k] * cW1[k * HID + f];
    a3 = fmaxf(a3, 0.0f);

    float prod = a3 * cW2[f];
#pragma unroll
    for (int off = 32; off > 0; off >>= 1) prod += __shfl_down(prod, off);
    if (f == 0) out[g] = prod + cb2[0];
}

extern "C" void kernel_launch(void* const* d_in, const int* in_sizes, int n_in,
                              void* d_out, int out_size, void* d_ws, size_t ws_size,
                              hipStream_t stream) {
    const float* x     = (const float*)d_in[0];
    const int*   ei    = (const int*)d_in[1];
    const int*   batch = (const int*)d_in[2];
    const float* gf    = (const float*)d_in[3];
    const float* W1    = (const float*)d_in[4];
    const float* b1    = (const float*)d_in[5];
    const float* W2    = (const float*)d_in[6];
    const float* b2    = (const float*)d_in[7];
    const float* gW1   = (const float*)d_in[8];
    const float* gb1   = (const float*)d_in[9];
    const float* gW2   = (const float*)d_in[10];
    const float* gb2   = (const float*)d_in[11];
    const float* cW1   = (const float*)d_in[12];
    const float* cb1   = (const float*)d_in[13];
    const float* cW2   = (const float*)d_in[14];
    const float* cb2   = (const float*)d_in[15];
    float* out = (float*)d_out;

    const int* src = ei;
    const int* dst = ei + N_EDGES;

    // workspace layout
    char* w = (char*)d_ws;
    half_t* Hs      = (half_t*)w; w += (size_t)N_NODES * HID * sizeof(half_t);  // 12.8 MB
    float*  bufB    = (float*)w;  w += (size_t)N_NODES * HID * sizeof(float);   // 25.6 MB
    int*    indeg   = (int*)w;    w += (size_t)N_NODES * sizeof(int);
    float*  dinv    = (float*)w;  w += (size_t)N_NODES * sizeof(float);
    int*    rowoff  = (int*)w;    w += (size_t)(N_NODES + 1) * sizeof(int);
    int*    cursor  = (int*)w;    w += (size_t)N_NODES * sizeof(int);
    int*    csrc    = (int*)w;    w += (size_t)N_EDGES * sizeof(int);
    int*    blocksum= (int*)w;    w += (size_t)SCAN_NB * sizeof(int);
    float*  pooled  = (float*)w;  w += (size_t)N_GRAPHS * HID * sizeof(float);

    const int BT = 256;

    // ---- CSR build ----
    hipMemsetAsync(indeg, 0, (size_t)N_NODES * sizeof(int), stream);
    k_indeg<<<P_PART * W_PART, BT, 0, stream>>>(dst, indeg, N_EDGES);
    k_scan1<<<SCAN_NB, BT, 0, stream>>>(indeg, blocksum, N_NODES);
    k_scan2<<<1, 128, 0, stream>>>(blocksum, SCAN_NB);
    k_scan3<<<SCAN_NB, BT, 0, stream>>>(indeg, blocksum, rowoff, cursor, dinv, N_NODES);
    k_bucket<<<P_PART * W_PART, BT, 0, stream>>>(src, dst, cursor, csrc, N_EDGES);

    // ---- conv1 ----
    k_mm<NODE_F><<<N_NODES / 16, BT, 0, stream>>>(x, W1, dinv, Hs, N_NODES);
    k_gather<1><<<(N_NODES + 3) / 4, BT, 0, stream>>>(Hs, rowoff, csrc, dinv, b1, bufB, N_NODES);

    // ---- conv2 (dense out, no atomics) ----
    k_mm<HID><<<N_NODES / 16, BT, 0, stream>>>(bufB, W2, dinv, Hs, N_NODES);
    k_gather<0><<<(N_NODES + 3) / 4, BT, 0, stream>>>(Hs, rowoff, csrc, dinv, b2, bufB, N_NODES);

    // ---- segment mean-pool ----
    k_pool<<<N_GRAPHS, BT, 0, stream>>>(bufB, batch, pooled, N_NODES);

    // ---- MLP head ----
    k_head<<<N_GRAPHS, HID, 0, stream>>>(pooled, gf, gW1, gb1, gW2, gb2,
                                         cW1, cb1, cW2, cb2, out);
}

// Round 8
// 337.025 us; speedup vs baseline: 2.2289x; 1.0423x over previous
//
#include <hip/hip_runtime.h>

#define N_NODES  100000
#define N_EDGES  1600000
#define N_GRAPHS 1024
#define NODE_F   100
#define HID      64
#define GLOB_F   3

#define SCAN_CHUNK 1024
#define SCAN_NB    ((N_NODES + SCAN_CHUNK - 1) / SCAN_CHUNK)   // 98

// dst-range partitioning for indeg/bucket (write-locality).
// Partition id = blockIdx.x % 8 -> under round-robin block->XCD dispatch, each
// partition's blocks all land on ONE XCD, so its ~800KB cursor/csrc window
// stays in a single L2 (heuristic: affects locality only, not correctness).
#define P_PART     8
#define W_PART     1024
#define R_PART     ((N_NODES + P_PART - 1) / P_PART)           // 12500 nodes/partition
#define CHUNK_PART ((N_EDGES + W_PART - 1) / W_PART)           // 1563 edges/block

typedef _Float16 half_t;
typedef __attribute__((ext_vector_type(8))) _Float16 half8;

// ---------------- degree, partition-filtered, XCD-affine ----------------
__global__ void k_indeg(const int* __restrict__ dst, int* __restrict__ indeg, int E) {
    int p = blockIdx.x % P_PART;          // ~ XCD id
    int w = blockIdx.x / P_PART;
    int lo_node = p * R_PART;
    int start = w * CHUNK_PART;
    int end = start + CHUNK_PART; if (end > E) end = E;
    for (int i = start + (int)threadIdx.x; i < end; i += 256) {
        int d = dst[i];
        if ((unsigned)(d - lo_node) < (unsigned)R_PART) atomicAdd(&indeg[d], 1);
    }
}

// ---------------- multi-block exclusive scan ----------------
__global__ void k_scan1(const int* __restrict__ indeg, int* __restrict__ blocksum, int N) {
    __shared__ int red[256];
    int t = threadIdx.x;
    int base = blockIdx.x * SCAN_CHUNK + t * 4;
    int s = 0;
#pragma unroll
    for (int j = 0; j < 4; ++j) { int i = base + j; if (i < N) s += indeg[i]; }
    red[t] = s;
    __syncthreads();
    for (int off = 128; off > 0; off >>= 1) {
        if (t < off) red[t] += red[t + off];
        __syncthreads();
    }
    if (t == 0) blocksum[blockIdx.x] = red[0];
}

__global__ void k_scan2(int* __restrict__ blocksum, int NB) {
    __shared__ int sh[128];
    int t = threadIdx.x;
    int v = (t < NB) ? blocksum[t] : 0;
    sh[t] = v;
    __syncthreads();
    for (int off = 1; off < 128; off <<= 1) {
        int o = (t >= off) ? sh[t - off] : 0;
        __syncthreads();
        sh[t] += o;
        __syncthreads();
    }
    if (t < NB) blocksum[t] = sh[t] - v;   // exclusive
}

__global__ void k_scan3(const int* __restrict__ indeg, const int* __restrict__ blocksum,
                        int* __restrict__ rowoff, int* __restrict__ cursor,
                        float* __restrict__ dinv, int N) {
    __shared__ int sh[256];
    int t = threadIdx.x;
    int base = blockIdx.x * SCAN_CHUNK + t * 4;
    int loc[4];
    int s = 0;
#pragma unroll
    for (int j = 0; j < 4; ++j) {
        int i = base + j;
        loc[j] = (i < N) ? indeg[i] : 0;
        s += loc[j];
    }
    sh[t] = s;
    __syncthreads();
    for (int off = 1; off < 256; off <<= 1) {
        int o = (t >= off) ? sh[t - off] : 0;
        __syncthreads();
        sh[t] += o;
        __syncthreads();
    }
    int run = blocksum[blockIdx.x] + sh[t] - s;
#pragma unroll
    for (int j = 0; j < 4; ++j) {
        int i = base + j;
        if (i < N) {
            rowoff[i] = run;
            cursor[i] = run;
            dinv[i] = 1.0f / sqrtf((float)(1 + loc[j]));
            run += loc[j];
            if (i == N - 1) rowoff[N] = run;
        }
    }
}

// ---------------- bucket, partition-filtered, XCD-affine ----------------
__global__ void k_bucket(const int* __restrict__ src, const int* __restrict__ dst,
                         int* __restrict__ cursor, int* __restrict__ csrc, int E) {
    int p = blockIdx.x % P_PART;          // ~ XCD id
    int w = blockIdx.x / P_PART;
    int lo_node = p * R_PART;
    int start = w * CHUNK_PART;
    int end = start + CHUNK_PART; if (end > E) end = E;
    for (int i = start + (int)threadIdx.x; i < end; i += 256) {
        int d = dst[i];
        if ((unsigned)(d - lo_node) < (unsigned)R_PART) {
            int pos = atomicAdd(&cursor[d], 1);
            csrc[pos] = src[i];
        }
    }
}

// ---------------- dense MM: W column in VGPRs, X broadcast from LDS ----------------
template <int K>
__launch_bounds__(256, 3)
__global__ void k_mm(const float* __restrict__ X, const float* __restrict__ W,
                     const float* __restrict__ dinv, half_t* __restrict__ Y, int N) {
    __shared__ float Xs[16 * K];
    int tid = threadIdx.x;
    int row0 = blockIdx.x * 16;

    const float4* Xg = reinterpret_cast<const float4*>(X + (size_t)row0 * K);
    float4* Xls = reinterpret_cast<float4*>(Xs);
    for (int i = tid; i < 16 * K / 4; i += 256) Xls[i] = Xg[i];

    int lane = tid & 63;
    int wv = tid >> 6;

    float Wr[K];
#pragma unroll
    for (int k = 0; k < K; ++k) Wr[k] = W[k * HID + lane];
    __syncthreads();

#pragma unroll
    for (int rr = 0; rr < 4; ++rr) {
        int r = row0 + wv * 4 + rr;
        const float4* xrow = reinterpret_cast<const float4*>(&Xs[(wv * 4 + rr) * K]);
        float acc0 = 0.f, acc1 = 0.f, acc2 = 0.f, acc3 = 0.f;
#pragma unroll
        for (int k4 = 0; k4 < K / 4; ++k4) {
            float4 xv = xrow[k4];
            acc0 += xv.x * Wr[k4 * 4 + 0];
            acc1 += xv.y * Wr[k4 * 4 + 1];
            acc2 += xv.z * Wr[k4 * 4 + 2];
            acc3 += xv.w * Wr[k4 * 4 + 3];
        }
        float acc = (acc0 + acc1) + (acc2 + acc3);
        Y[(size_t)r * HID + lane] = (half_t)(acc * dinv[r]);
    }
}

// ---------------- per-dst gather, fp16 payload -> dense f32 out ----------------
template <int RELU>
__global__ void k_gather(const half_t* __restrict__ Hs, const int* __restrict__ rowoff,
                         const int* __restrict__ csrc, const float* __restrict__ dinv,
                         const float* __restrict__ b, float* __restrict__ outbuf, int N) {
    int tid = threadIdx.x;
    int d = blockIdx.x * 4 + (tid >> 6);
    if (d >= N) return;
    int lane = tid & 63;
    int g = lane >> 3;
    int l = lane & 7;
    int lo = rowoff[d], hi = rowoff[d + 1];

    float acc[8] = {0, 0, 0, 0, 0, 0, 0, 0};

    int e = lo;
    for (; e + 16 <= hi; e += 16) {
        int s0 = csrc[e + g];
        int s1 = csrc[e + 8 + g];
        half8 h0 = *reinterpret_cast<const half8*>(Hs + (size_t)s0 * HID + l * 8);
        half8 h1 = *reinterpret_cast<const half8*>(Hs + (size_t)s1 * HID + l * 8);
#pragma unroll
        for (int j = 0; j < 8; ++j) acc[j] += (float)h0[j];
#pragma unroll
        for (int j = 0; j < 8; ++j) acc[j] += (float)h1[j];
    }
    for (; e < hi; e += 8) {
        int ee = e + g;
        if (ee < hi) {
            int s = csrc[ee];
            half8 hv = *reinterpret_cast<const half8*>(Hs + (size_t)s * HID + l * 8);
#pragma unroll
            for (int j = 0; j < 8; ++j) acc[j] += (float)hv[j];
        }
    }
    if (g == 0) {   // self-loop row
        half8 hv = *reinterpret_cast<const half8*>(Hs + (size_t)d * HID + l * 8);
#pragma unroll
        for (int j = 0; j < 8; ++j) acc[j] += (float)hv[j];
    }
#pragma unroll
    for (int off = 8; off <= 32; off <<= 1) {
#pragma unroll
        for (int j = 0; j < 8; ++j) acc[j] += __shfl_xor(acc[j], off);
    }

    if (g == 0) {
        float dd = dinv[d];
        float v[8];
#pragma unroll
        for (int j = 0; j < 8; ++j) {
            v[j] = acc[j] * dd + b[l * 8 + j];
            if (RELU) v[j] = fmaxf(v[j], 0.0f);
        }
        float4* o = reinterpret_cast<float4*>(outbuf + (size_t)d * HID + l * 8);
        o[0] = make_float4(v[0], v[1], v[2], v[3]);
        o[1] = make_float4(v[4], v[5], v[6], v[7]);
    }
}

// ---------------- segment mean-pool: one block per graph, batch sorted ----------------
__global__ void k_pool(const float* __restrict__ H, const int* __restrict__ batch,
                       float* __restrict__ pooled, int N) {
    int g = blockIdx.x;
    __shared__ int sh_lo, sh_hi;
    __shared__ float red[4][HID];
    if (threadIdx.x == 0) {
        int lo = 0, hi = N;
        while (lo < hi) { int m = (lo + hi) >> 1; if (batch[m] < g) lo = m + 1; else hi = m; }
        sh_lo = lo;
        int lo2 = lo, hi2 = N;
        while (lo2 < hi2) { int m = (lo2 + hi2) >> 1; if (batch[m] < g + 1) lo2 = m + 1; else hi2 = m; }
        sh_hi = lo2;
    }
    __syncthreads();
    int lo = sh_lo, hi = sh_hi;
    int wave = threadIdx.x >> 6, lane = threadIdx.x & 63;
    float acc = 0.0f;
    for (int i = lo + wave; i < hi; i += 4)
        acc += H[(size_t)i * HID + lane];
    red[wave][lane] = acc;
    __syncthreads();
    if (wave == 0) {
        float s = red[0][lane] + red[1][lane] + red[2][lane] + red[3][lane];
        int c = hi - lo;
        pooled[g * HID + lane] = s / (float)(c > 0 ? c : 1);
    }
}

// ---------------- MLP head: one wave per graph ----------------
__global__ void k_head(const float* __restrict__ pooled,
                       const float* __restrict__ gf,
                       const float* __restrict__ gW1, const float* __restrict__ gb1,
                       const float* __restrict__ gW2, const float* __restrict__ gb2,
                       const float* __restrict__ cW1, const float* __restrict__ cb1,
                       const float* __restrict__ cW2, const float* __restrict__ cb2,
                       float* __restrict__ out) {
    int g = blockIdx.x;
    int f = threadIdx.x;
    __shared__ float gh[HID];
    __shared__ float comb[2 * HID];

    float a = gb1[f];
#pragma unroll
    for (int k = 0; k < GLOB_F; ++k) a += gf[g * GLOB_F + k] * gW1[k * HID + f];
    gh[f] = fmaxf(a, 0.0f);
    __syncthreads();

    float a2 = gb2[f];
#pragma unroll 8
    for (int k = 0; k < HID; ++k) a2 += gh[k] * gW2[k * HID + f];

    comb[f] = pooled[g * HID + f];
    comb[HID + f] = a2;
    __syncthreads();

    float a3 = cb1[f];
#pragma unroll 8
    for (int k = 0; k < 2 * HID; ++k) a3 += comb[k] * cW1[k * HID + f];
    a3 = fmaxf(a3, 0.0f);

    float prod = a3 * cW2[f];
#pragma unroll
    for (int off = 32; off > 0; off >>= 1) prod += __shfl_down(prod, off);
    if (f == 0) out[g] = prod + cb2[0];
}

extern "C" void kernel_launch(void* const* d_in, const int* in_sizes, int n_in,
                              void* d_out, int out_size, void* d_ws, size_t ws_size,
                              hipStream_t stream) {
    const float* x     = (const float*)d_in[0];
    const int*   ei    = (const int*)d_in[1];
    const int*   batch = (const int*)d_in[2];
    const float* gf    = (const float*)d_in[3];
    const float* W1    = (const float*)d_in[4];
    const float* b1    = (const float*)d_in[5];
    const float* W2    = (const float*)d_in[6];
    const float* b2    = (const float*)d_in[7];
    const float* gW1   = (const float*)d_in[8];
    const float* gb1   = (const float*)d_in[9];
    const float* gW2   = (const float*)d_in[10];
    const float* gb2   = (const float*)d_in[11];
    const float* cW1   = (const float*)d_in[12];
    const float* cb1   = (const float*)d_in[13];
    const float* cW2   = (const float*)d_in[14];
    const float* cb2   = (const float*)d_in[15];
    float* out = (float*)d_out;

    const int* src = ei;
    const int* dst = ei + N_EDGES;

    // workspace layout
    char* w = (char*)d_ws;
    half_t* Hs      = (half_t*)w; w += (size_t)N_NODES * HID * sizeof(half_t);  // 12.8 MB
    float*  bufB    = (float*)w;  w += (size_t)N_NODES * HID * sizeof(float);   // 25.6 MB
    int*    indeg   = (int*)w;    w += (size_t)N_NODES * sizeof(int);
    float*  dinv    = (float*)w;  w += (size_t)N_NODES * sizeof(float);
    int*    rowoff  = (int*)w;    w += (size_t)(N_NODES + 1) * sizeof(int);
    int*    cursor  = (int*)w;    w += (size_t)N_NODES * sizeof(int);
    int*    csrc    = (int*)w;    w += (size_t)N_EDGES * sizeof(int);
    int*    blocksum= (int*)w;    w += (size_t)SCAN_NB * sizeof(int);
    float*  pooled  = (float*)w;  w += (size_t)N_GRAPHS * HID * sizeof(float);

    const int BT = 256;

    // ---- CSR build ----
    hipMemsetAsync(indeg, 0, (size_t)N_NODES * sizeof(int), stream);
    k_indeg<<<P_PART * W_PART, BT, 0, stream>>>(dst, indeg, N_EDGES);
    k_scan1<<<SCAN_NB, BT, 0, stream>>>(indeg, blocksum, N_NODES);
    k_scan2<<<1, 128, 0, stream>>>(blocksum, SCAN_NB);
    k_scan3<<<SCAN_NB, BT, 0, stream>>>(indeg, blocksum, rowoff, cursor, dinv, N_NODES);
    k_bucket<<<P_PART * W_PART, BT, 0, stream>>>(src, dst, cursor, csrc, N_EDGES);

    // ---- conv1 ----
    k_mm<NODE_F><<<N_NODES / 16, BT, 0, stream>>>(x, W1, dinv, Hs, N_NODES);
    k_gather<1><<<(N_NODES + 3) / 4, BT, 0, stream>>>(Hs, rowoff, csrc, dinv, b1, bufB, N_NODES);

    // ---- conv2 (dense out, no atomics) ----
    k_mm<HID><<<N_NODES / 16, BT, 0, stream>>>(bufB, W2, dinv, Hs, N_NODES);
    k_gather<0><<<(N_NODES + 3) / 4, BT, 0, stream>>>(Hs, rowoff, csrc, dinv, b2, bufB, N_NODES);

    // ---- segment mean-pool ----
    k_pool<<<N_GRAPHS, BT, 0, stream>>>(bufB, batch, pooled, N_NODES);

    // ---- MLP head ----
    k_head<<<N_GRAPHS, HID, 0, stream>>>(pooled, gf, gW1, gb1, gW2, gb2,
                                         cW1, cb1, cW2, cb2, out);
}